// Round 6
// baseline (133.371 us; speedup 1.0000x reference)
//
#include <hip/hip_runtime.h>
#include <math.h>

#define N 256
#define NN (N * N)      // 65536
#define NNN (N * N * N) // 16777216

__device__ inline float4 f4max(float4 a, float4 b) {
  return make_float4(fmaxf(a.x, b.x), fmaxf(a.y, b.y), fmaxf(a.z, b.z), fmaxf(a.w, b.w));
}
__device__ inline float4 f4add(float4 a, float4 b) {
  return make_float4(a.x + b.x, a.y + b.y, a.z + b.z, a.w + b.w);
}

// ===== fused reduction kernel =====
// blocks [0, BN):      bc-branch: block = (b,c) reads c-plane x[b,c,:,:]
//                      (256 KiB CONTIGUOUS). Produces complete:
//                        zB[b][c][w]  = max/mean over h
//                        zCT[b][c][h] = max/mean over w   (transposed layout!)
// blocks [BN, 2BN):    a-branch: block = (b, h-pair, c-half), STRIDED but
//                      pure-elementwise (no shfl/LDS in loop). Produces:
//                        zA{half}[b][h][w] partial (merged in conv)
struct LdsBC {
  float pms[256][9][2];  // per-row 8 w-partials (pad 9) x (m,s)
  float gm[4][N];        // per-wave elementwise max partial
  float gs[4][N];        // per-wave elementwise sum partial
};
struct LdsA {
  float am[4][2][N];     // [wave][h0/h1][w] max partials
  float as[4][2][N];     // [wave][h0/h1][w] sum partials
};

__global__ __launch_bounds__(256) void reduce_fused_kernel(
    const float* __restrict__ x,
    float* __restrict__ zA0max, float* __restrict__ zA0mean,
    float* __restrict__ zA1max, float* __restrict__ zA1mean,
    float* __restrict__ zBmax, float* __restrict__ zBmean,
    float* __restrict__ zCTmax, float* __restrict__ zCTmean,
    int BN) {
  __shared__ __align__(16) char lds_raw[sizeof(LdsBC)];
  const int lane = threadIdx.x & 63;
  const int g = threadIdx.x >> 6;  // wave 0..3

  if ((int)blockIdx.x < BN) {
    // ---------------- bc-branch: contiguous c-plane ----------------
    LdsBC& L = *reinterpret_cast<LdsBC*>(lds_raw);
    const int bc = blockIdx.x;        // b*N + c
    const int b = bc >> 8, c = bc & 255;
    // wave g owns h rows [64g, 64g+64): contiguous 64 KiB
    const float* p = x + (size_t)b * NNN + (size_t)c * NN + (size_t)(g * 64) * N + (lane << 2);
    float4 m4 = make_float4(-INFINITY, -INFINITY, -INFINITY, -INFINITY);
    float4 s4 = make_float4(0.f, 0.f, 0.f, 0.f);
#pragma unroll 4
    for (int hh = 0; hh < 64; ++hh) {
      float4 v = *(const float4*)(p + (size_t)hh * N);
      // zB: elementwise over h
      m4 = f4max(m4, v);
      s4 = f4add(s4, v);
      // zC: per-row w-reduce partials (3 shfl levels -> 8 partials/row)
      float m = fmaxf(fmaxf(v.x, v.y), fmaxf(v.z, v.w));
      float s = (v.x + v.y) + (v.z + v.w);
      m = fmaxf(m, __shfl_xor(m, 1));
      s += __shfl_xor(s, 1);
      m = fmaxf(m, __shfl_xor(m, 2));
      s += __shfl_xor(s, 2);
      m = fmaxf(m, __shfl_xor(m, 4));
      s += __shfl_xor(s, 4);
      if ((lane & 7) == 0) {
        const int h = (g << 6) + hh;
        L.pms[h][lane >> 3][0] = m;
        L.pms[h][lane >> 3][1] = s;
      }
    }
    const int w4 = lane << 2;
    *(float4*)&L.gm[g][w4] = m4;
    *(float4*)&L.gs[g][w4] = s4;
    __syncthreads();
    const int t = threadIdx.x;
    // zB finalize (w = t)
    {
      float m = fmaxf(fmaxf(L.gm[0][t], L.gm[1][t]), fmaxf(L.gm[2][t], L.gm[3][t]));
      float s = (L.gs[0][t] + L.gs[1][t] + L.gs[2][t] + L.gs[3][t]) * (1.f / 256.f);
      zBmax[(size_t)bc * N + t] = m;
      zBmean[(size_t)bc * N + t] = s;
    }
    // zCT finalize (h = t): fold 8 partials; coalesced column write
    {
      float m = L.pms[t][0][0];
      float s = L.pms[t][0][1];
#pragma unroll
      for (int i = 1; i < 8; ++i) {
        m = fmaxf(m, L.pms[t][i][0]);
        s += L.pms[t][i][1];
      }
      zCTmax[(size_t)bc * N + t] = m;
      zCTmean[(size_t)bc * N + t] = s * (1.f / 256.f);
    }
  } else {
    // ---------------- a-branch: strided, pure elementwise ----------------
    LdsA& L = *reinterpret_cast<LdsA*>(lds_raw);
    const int idx = blockIdx.x - BN;       // [0, 512)
    const int b = idx >> 8;
    const int rem = idx & 255;
    const int hp = rem >> 1;               // h-pair 0..127
    const int chalf = rem & 1;
    const int h0 = hp << 1;
    // wave g handles c = chalf*128 + g + 4*step
    const float* p = x + (size_t)b * NNN + (size_t)(chalf * 128 + g) * NN +
                     (size_t)h0 * N + (lane << 2);
    float4 ma = make_float4(-INFINITY, -INFINITY, -INFINITY, -INFINITY);
    float4 sa = make_float4(0.f, 0.f, 0.f, 0.f);
    float4 mb = ma;
    float4 sb = sa;
#pragma unroll 4
    for (int st = 0; st < 32; ++st) {
      const float* q = p + (size_t)(st * 4) * NN;
      float4 v0 = *(const float4*)(q);
      float4 v1 = *(const float4*)(q + N);
      ma = f4max(ma, v0);
      sa = f4add(sa, v0);
      mb = f4max(mb, v1);
      sb = f4add(sb, v1);
    }
    const int w4 = lane << 2;
    *(float4*)&L.am[g][0][w4] = ma;
    *(float4*)&L.as[g][0][w4] = sa;
    *(float4*)&L.am[g][1][w4] = mb;
    *(float4*)&L.as[g][1][w4] = sb;
    __syncthreads();
    const int t = threadIdx.x;
    float* zm = chalf ? zA1max : zA0max;
    float* zs = chalf ? zA1mean : zA0mean;
#pragma unroll
    for (int r = 0; r < 2; ++r) {
      float m = fmaxf(fmaxf(L.am[0][r][t], L.am[1][r][t]), fmaxf(L.am[2][r][t], L.am[3][r][t]));
      float s = (L.as[0][r][t] + L.as[1][r][t] + L.as[2][r][t] + L.as[3][r][t]) * (1.f / 256.f);
      const size_t o = ((size_t)(b << 8) + (h0 + r)) * N + t;
      zm[o] = m;
      zs[o] = s;
    }
  }
}

// -------- fused 7x7 conv (2ch->1) + BN + sigmoid for ALL THREE gates --------
// branch 0 (hw): zA dual-half merge, in [b][h][w], out Ghw[b][h][w]
// branch 1 (hc): zB single,          in [b][c][w], out Ghc[b][c][w]
// branch 2 (wc): zCT TRANSPOSED [b][c][h]; block=(b,c), thread=h (coalesced
//                reads along h), out Gwc[b][h][c]
__global__ __launch_bounds__(256) void conv_gate3_kernel(
    const float* __restrict__ zA0max, const float* __restrict__ zA0mean,
    const float* __restrict__ zA1max, const float* __restrict__ zA1mean,
    const float* __restrict__ zBmax, const float* __restrict__ zBmean,
    const float* __restrict__ zCTmax, const float* __restrict__ zCTmean,
    const float* __restrict__ w_hw, const float* __restrict__ g_hw,
    const float* __restrict__ b_hw, const float* __restrict__ m_hw,
    const float* __restrict__ v_hw,
    const float* __restrict__ w_hc, const float* __restrict__ g_hc,
    const float* __restrict__ b_hc, const float* __restrict__ m_hc,
    const float* __restrict__ v_hc,
    const float* __restrict__ w_wc, const float* __restrict__ g_wc,
    const float* __restrict__ b_wc, const float* __restrict__ m_wc,
    const float* __restrict__ v_wc,
    float* __restrict__ Ghw, float* __restrict__ Ghc, float* __restrict__ Gwc,
    int BN) {
  const int branch = blockIdx.x / BN;
  const int bp = blockIdx.x - branch * BN;  // b*N + (p or c)
  const int b = bp >> 8;
  const size_t boff = (size_t)b * NN;

  if (branch == 2) {
    // wc: block c-column, thread = h
    const int c = bp & 255;
    const int h = threadIdx.x;
    const float* zm = zCTmax + boff;
    const float* za = zCTmean + boff;
    float y = 0.f;
#pragma unroll
    for (int dc = 0; dc < 7; ++dc) {
      const int cc = c + dc - 3;
      if ((unsigned)cc < N) {
#pragma unroll
        for (int dh = 0; dh < 7; ++dh) {
          const int hh = h + dh - 3;
          if ((unsigned)hh < N) {
            const int idx = cc * N + hh;
            y += zm[idx] * w_wc[dh * 7 + dc] + za[idx] * w_wc[49 + dh * 7 + dc];
          }
        }
      }
    }
    const float scale = g_wc[0] * rsqrtf(v_wc[0] + 1e-5f);
    const float yb = (y - m_wc[0]) * scale + b_wc[0];
    Gwc[boff + (size_t)h * N + c] = 1.f / (1.f + __expf(-yb));
    return;
  }

  const int p = bp & 255;
  const int q = threadIdx.x;
  const float *zm0, *zm1, *za0, *za1;
  const float *wt, *gg, *bb, *mm, *vv;
  float* gate;
  bool dual;
  if (branch == 0) {
    zm0 = zA0max; zm1 = zA1max; za0 = zA0mean; za1 = zA1mean; dual = true;
    wt = w_hw; gg = g_hw; bb = b_hw; mm = m_hw; vv = v_hw; gate = Ghw;
  } else {
    zm0 = zBmax; zm1 = zBmax; za0 = zBmean; za1 = zBmean; dual = false;
    wt = w_hc; gg = g_hc; bb = b_hc; mm = m_hc; vv = v_hc; gate = Ghc;
  }
  zm0 += boff; zm1 += boff; za0 += boff; za1 += boff;
  float y = 0.f;
#pragma unroll
  for (int dh = 0; dh < 7; ++dh) {
    const int pp = p + dh - 3;
    if ((unsigned)pp < N) {
#pragma unroll
      for (int dw = 0; dw < 7; ++dw) {
        const int qq = q + dw - 3;
        if ((unsigned)qq < N) {
          const int idx = pp * N + qq;
          const float zm = dual ? fmaxf(zm0[idx], zm1[idx]) : zm0[idx];
          const float za = dual ? (za0[idx] + za1[idx]) : za0[idx];
          y += zm * wt[dh * 7 + dw] + za * wt[49 + dh * 7 + dw];
        }
      }
    }
  }
  const float scale = gg[0] * rsqrtf(vv[0] + 1e-5f);
  const float yb = (y - mm[0]) * scale + bb[0];
  gate[boff + (size_t)p * N + q] = 1.f / (1.f + __expf(-yb));
}

// -------- final combine --------
// out[b,i,j,k] = ( x[b,i,j,k]*(Ghw[b,j,k]+Ghc[b,i,k]) + x[b,k,i,j]*Gwc[b,i,k] ) / 3
__global__ __launch_bounds__(256) void combine_kernel(
    const float* __restrict__ x, const float* __restrict__ Ghw,
    const float* __restrict__ Ghc, const float* __restrict__ Gwc,
    float* __restrict__ out) {
  __shared__ float t[32][33]; // t[kk][jj] = x[b, k0+kk, i, j0+jj]
  const int blk = blockIdx.x;
  const int kt = blk & 7, jt = (blk >> 3) & 7, i = (blk >> 6) & 255, b = blk >> 14;
  const int k0 = kt << 5, j0 = jt << 5;
  const int rowi = threadIdx.x >> 3;        // 0..31
  const int col4 = (threadIdx.x & 7) << 2;  // 0,4,...,28
  {
    float4 v = *(const float4*)(x + ((size_t)b << 24) + ((size_t)(k0 + rowi) << 16) +
                                ((size_t)i << 8) + j0 + col4);
    t[rowi][col4 + 0] = v.x;
    t[rowi][col4 + 1] = v.y;
    t[rowi][col4 + 2] = v.z;
    t[rowi][col4 + 3] = v.w;
  }
  __syncthreads();
  const int jj = rowi;        // output row within tile
  const int k = k0 + col4;    // output col quad
  const size_t gik = (((size_t)(b << 8) + i) << 8) + k; // (b*N+i)*N + k
  const float4 ghc = *(const float4*)(Ghc + gik);
  const float4 gwc = *(const float4*)(Gwc + gik);
  const size_t base = ((size_t)b << 24) + ((size_t)i << 16) + ((size_t)(j0 + jj) << 8) + k;
  const float4 xv = *(const float4*)(x + base);
  const float4 ghw = *(const float4*)(Ghw + ((size_t)b << 16) + ((size_t)(j0 + jj) << 8) + k);
  const float third = 1.f / 3.f;
  float4 r;
  r.x = (xv.x * (ghw.x + ghc.x) + t[col4 + 0][jj] * gwc.x) * third;
  r.y = (xv.y * (ghw.y + ghc.y) + t[col4 + 1][jj] * gwc.y) * third;
  r.z = (xv.z * (ghw.z + ghc.z) + t[col4 + 2][jj] * gwc.z) * third;
  r.w = (xv.w * (ghw.w + ghc.w) + t[col4 + 3][jj] * gwc.w) * third;
  *(float4*)(out + base) = r;
}

extern "C" void kernel_launch(void* const* d_in, const int* in_sizes, int n_in,
                              void* d_out, int out_size, void* d_ws, size_t ws_size,
                              hipStream_t stream) {
  const float* x    = (const float*)d_in[0];
  const float* w_hw = (const float*)d_in[1];
  const float* g_hw = (const float*)d_in[2];
  const float* b_hw = (const float*)d_in[3];
  const float* m_hw = (const float*)d_in[4];
  const float* v_hw = (const float*)d_in[5];
  const float* w_hc = (const float*)d_in[6];
  const float* g_hc = (const float*)d_in[7];
  const float* b_hc = (const float*)d_in[8];
  const float* m_hc = (const float*)d_in[9];
  const float* v_hc = (const float*)d_in[10];
  const float* w_wc = (const float*)d_in[11];
  const float* g_wc = (const float*)d_in[12];
  const float* b_wc = (const float*)d_in[13];
  const float* m_wc = (const float*)d_in[14];
  const float* v_wc = (const float*)d_in[15];

  const int B = in_sizes[0] / NNN; // 2
  const int BN = B * N;
  const size_t plane = (size_t)B * NN;
  float* ws = (float*)d_ws;
  float* zA0max  = ws + 0 * plane;
  float* zA0mean = ws + 1 * plane;
  float* zA1max  = ws + 2 * plane;
  float* zA1mean = ws + 3 * plane;
  float* zBmax   = ws + 4 * plane;
  float* zBmean  = ws + 5 * plane;
  float* zCTmax  = ws + 6 * plane;
  float* zCTmean = ws + 7 * plane;
  float* GhwP    = ws + 8 * plane;
  float* GhcP    = ws + 9 * plane;
  float* GwcP    = ws + 10 * plane;

  reduce_fused_kernel<<<2 * BN, 256, 0, stream>>>(
      x, zA0max, zA0mean, zA1max, zA1mean,
      zBmax, zBmean, zCTmax, zCTmean, BN);

  conv_gate3_kernel<<<3 * BN, 256, 0, stream>>>(
      zA0max, zA0mean, zA1max, zA1mean,
      zBmax, zBmean, zCTmax, zCTmean,
      w_hw, g_hw, b_hw, m_hw, v_hw,
      w_hc, g_hc, b_hc, m_hc, v_hc,
      w_wc, g_wc, b_wc, m_wc, v_wc,
      GhwP, GhcP, GwcP, BN);

  combine_kernel<<<B * N * 64, 256, 0, stream>>>(x, GhwP, GhcP, GwcP, (float*)d_out);
}